// Round 1
// baseline (10521.594 us; speedup 1.0000x reference)
//
#include <hip/hip_runtime.h>
#include <hip/hip_bf16.h>

static constexpr float kLog2 = 0.6931471805599453f;

// shifted softplus: softplus(x) - log(2), numerically stable
__device__ __forceinline__ float sspf(float x) {
    return fmaxf(x, 0.0f) + __logf(1.0f + __expf(-fabsf(x))) - kLog2;
}

// C[m][f] = act(bias[f] + sum_k A[m][k] * B[f][k])
// A: [M][128] row-major, B: [128][128] row-major (row = output channel, col = k)
// 64-row tile per block, 256 threads, 4x8 micro-tile per thread.
// LDS stride 68: bank-start (4*row+kk)%32 -> <=2-way conflicts (free).
template <bool ACT>
__global__ __launch_bounds__(256) void gemm128(const float* __restrict__ A,
                                               const float* __restrict__ B,
                                               const float* __restrict__ bias,
                                               float* __restrict__ C, int M) {
    __shared__ float As[64][68];
    __shared__ float Bs[128][68];
    const int tid = threadIdx.x;
    const int rowbase = blockIdx.x * 64;
    const int fx = tid & 15;   // f = fx + 16*j  (interleaved to dodge bank conflicts)
    const int ax = tid >> 4;   // row = ax*4 + i
    float acc[4][8];
#pragma unroll
    for (int i = 0; i < 4; ++i)
#pragma unroll
        for (int j = 0; j < 8; ++j) acc[i][j] = 0.0f;

    for (int k0 = 0; k0 < 128; k0 += 64) {
#pragma unroll
        for (int it = 0; it < 4; ++it) {
            int idx = it * 256 + tid;
            int r = idx >> 4, c = (idx & 15) << 2;
            int rg = rowbase + r;
            rg = rg < M ? rg : (M - 1);  // clamp reads, guard writes later
            *(float4*)&As[r][c] = *(const float4*)(A + (size_t)rg * 128 + k0 + c);
        }
#pragma unroll
        for (int it = 0; it < 8; ++it) {
            int idx = it * 256 + tid;
            int r = idx >> 4, c = (idx & 15) << 2;
            *(float4*)&Bs[r][c] = *(const float4*)(B + (size_t)r * 128 + k0 + c);
        }
        __syncthreads();
#pragma unroll
        for (int kk = 0; kk < 64; kk += 4) {
            float4 av[4], bv[8];
#pragma unroll
            for (int i = 0; i < 4; ++i) av[i] = *(const float4*)&As[ax * 4 + i][kk];
#pragma unroll
            for (int j = 0; j < 8; ++j) bv[j] = *(const float4*)&Bs[fx + j * 16][kk];
#pragma unroll
            for (int i = 0; i < 4; ++i)
#pragma unroll
                for (int j = 0; j < 8; ++j) {
                    acc[i][j] = fmaf(av[i].x, bv[j].x, acc[i][j]);
                    acc[i][j] = fmaf(av[i].y, bv[j].y, acc[i][j]);
                    acc[i][j] = fmaf(av[i].z, bv[j].z, acc[i][j]);
                    acc[i][j] = fmaf(av[i].w, bv[j].w, acc[i][j]);
                }
        }
        __syncthreads();
    }
#pragma unroll
    for (int i = 0; i < 4; ++i) {
        int rg = rowbase + ax * 4 + i;
        if (rg < M) {
#pragma unroll
            for (int j = 0; j < 8; ++j) {
                int f = fx + j * 16;
                float v = acc[i][j] + bias[f];
                if (ACT) v = sspf(v);
                C[(size_t)rg * 128 + f] = v;
            }
        }
    }
}

// One thread per edge. Filter GEMM (20->128) + ssp + *rcut + gather h[idx_j]
// + scatter-add into agg[idx_i]. W_filter indices are wave-uniform -> s_load.
__global__ __launch_bounds__(256) void edge_kernel(
    const float* __restrict__ f_ij, const int* __restrict__ idx_i,
    const int* __restrict__ idx_j, const float* __restrict__ rcut,
    const float* __restrict__ Wf, const float* __restrict__ bf,
    const float* __restrict__ h, float* __restrict__ agg, int P) {
    int p = blockIdx.x * 256 + threadIdx.x;
    if (p >= P) return;
    // f_ij row: 80 B, 16B-aligned (80 % 16 == 0) -> 5 float4 loads
    const float4* fr = (const float4*)(f_ij + (size_t)p * 20);
    float4 q0 = fr[0], q1 = fr[1], q2 = fr[2], q3 = fr[3], q4 = fr[4];
    float fij[20] = {q0.x, q0.y, q0.z, q0.w, q1.x, q1.y, q1.z, q1.w,
                     q2.x, q2.y, q2.z, q2.w, q3.x, q3.y, q3.z, q3.w,
                     q4.x, q4.y, q4.z, q4.w};
    const int jb = idx_j[p] * 128;
    const int ib = idx_i[p] * 128;
    const float rc = rcut[p];
    for (int f0 = 0; f0 < 128; f0 += 4) {
        float4 hv = *(const float4*)(h + jb + f0);
        float hvals[4] = {hv.x, hv.y, hv.z, hv.w};
#pragma unroll
        for (int ff = 0; ff < 4; ++ff) {
            int f = f0 + ff;
            float a = bf[f];
#pragma unroll
            for (int r = 0; r < 20; ++r) a = fmaf(fij[r], Wf[f * 20 + r], a);
            float w = sspf(a) * rc;
            unsafeAtomicAdd(&agg[ib + f], hvals[ff] * w);
        }
    }
}

extern "C" void kernel_launch(void* const* d_in, const int* in_sizes, int n_in,
                              void* d_out, int out_size, void* d_ws, size_t ws_size,
                              hipStream_t stream) {
    const float* x     = (const float*)d_in[0];
    const float* f_ij  = (const float*)d_in[1];
    const int*   idx_i = (const int*)d_in[2];
    const int*   idx_j = (const int*)d_in[3];
    const float* rcut  = (const float*)d_in[4];
    const float* W_in  = (const float*)d_in[5];
    const float* b_in  = (const float*)d_in[6];
    const float* W_f   = (const float*)d_in[7];
    const float* b_f   = (const float*)d_in[8];
    const float* W_out = (const float*)d_in[9];
    const float* b_out = (const float*)d_in[10];

    const int N = in_sizes[0] / 128;  // 50000 atoms
    const int P = in_sizes[2];        // 1600000 edges

    float* h   = (float*)d_out;  // h lives in d_out; consumed before final GEMM writes it
    float* agg = (float*)d_ws;   // 25.6 MB scratch

    const int mblocks = (N + 63) / 64;
    gemm128<false><<<mblocks, 256, 0, stream>>>(x, W_in, b_in, h, N);
    hipMemsetAsync(agg, 0, (size_t)N * 128 * sizeof(float), stream);
    edge_kernel<<<(P + 255) / 256, 256, 0, stream>>>(f_ij, idx_i, idx_j, rcut,
                                                     W_f, b_f, h, agg, P);
    gemm128<true><<<mblocks, 256, 0, stream>>>(agg, W_out, b_out, (float*)d_out, N);
}

// Round 2
// 1035.697 us; speedup vs baseline: 10.1590x; 10.1590x over previous
//
#include <hip/hip_runtime.h>
#include <hip/hip_bf16.h>

static constexpr float kLog2 = 0.6931471805599453f;

// shifted softplus: softplus(x) - log(2), numerically stable
__device__ __forceinline__ float sspf(float x) {
    return fmaxf(x, 0.0f) + __logf(1.0f + __expf(-fabsf(x))) - kLog2;
}

// C[m][f] = act(bias[f] + sum_k A[m][k] * B[f][k])
// A: [M][128] row-major, B: [128][128] row-major (row = output channel, col = k)
template <bool ACT>
__global__ __launch_bounds__(256) void gemm128(const float* __restrict__ A,
                                               const float* __restrict__ B,
                                               const float* __restrict__ bias,
                                               float* __restrict__ C, int M) {
    __shared__ float As[64][68];
    __shared__ float Bs[128][68];
    const int tid = threadIdx.x;
    const int rowbase = blockIdx.x * 64;
    const int fx = tid & 15;
    const int ax = tid >> 4;
    float acc[4][8];
#pragma unroll
    for (int i = 0; i < 4; ++i)
#pragma unroll
        for (int j = 0; j < 8; ++j) acc[i][j] = 0.0f;

    for (int k0 = 0; k0 < 128; k0 += 64) {
#pragma unroll
        for (int it = 0; it < 4; ++it) {
            int idx = it * 256 + tid;
            int r = idx >> 4, c = (idx & 15) << 2;
            int rg = rowbase + r;
            rg = rg < M ? rg : (M - 1);
            *(float4*)&As[r][c] = *(const float4*)(A + (size_t)rg * 128 + k0 + c);
        }
#pragma unroll
        for (int it = 0; it < 8; ++it) {
            int idx = it * 256 + tid;
            int r = idx >> 4, c = (idx & 15) << 2;
            *(float4*)&Bs[r][c] = *(const float4*)(B + (size_t)r * 128 + k0 + c);
        }
        __syncthreads();
#pragma unroll
        for (int kk = 0; kk < 64; kk += 4) {
            float4 av[4], bv[8];
#pragma unroll
            for (int i = 0; i < 4; ++i) av[i] = *(const float4*)&As[ax * 4 + i][kk];
#pragma unroll
            for (int j = 0; j < 8; ++j) bv[j] = *(const float4*)&Bs[fx + j * 16][kk];
#pragma unroll
            for (int i = 0; i < 4; ++i)
#pragma unroll
                for (int j = 0; j < 8; ++j) {
                    acc[i][j] = fmaf(av[i].x, bv[j].x, acc[i][j]);
                    acc[i][j] = fmaf(av[i].y, bv[j].y, acc[i][j]);
                    acc[i][j] = fmaf(av[i].z, bv[j].z, acc[i][j]);
                    acc[i][j] = fmaf(av[i].w, bv[j].w, acc[i][j]);
                }
        }
        __syncthreads();
    }
#pragma unroll
    for (int i = 0; i < 4; ++i) {
        int rg = rowbase + ax * 4 + i;
        if (rg < M) {
#pragma unroll
            for (int j = 0; j < 8; ++j) {
                int f = fx + j * 16;
                float v = acc[i][j] + bias[f];
                if (ACT) v = sspf(v);
                C[(size_t)rg * 128 + f] = v;
            }
        }
    }
}

// --- CSR build: counts -> exclusive scan -> fill ---

__global__ __launch_bounds__(256) void count_kernel(const int* __restrict__ idx_i,
                                                    int* __restrict__ counts, int P) {
    int p = blockIdx.x * 256 + threadIdx.x;
    if (p < P) atomicAdd(&counts[idx_i[p]], 1);
}

// single-block exclusive scan of counts[0..N) -> offsets[0..N], cursor copy
__global__ __launch_bounds__(1024) void scan_kernel(const int* __restrict__ counts,
                                                    int* __restrict__ offsets,
                                                    int* __restrict__ cursor, int N) {
    __shared__ int part[1024];
    const int t = threadIdx.x;
    const int CH = (N + 1023) / 1024;
    const int base = t * CH;
    int sum = 0;
    for (int k = 0; k < CH; ++k) {
        int idx = base + k;
        if (idx < N) sum += counts[idx];
    }
    part[t] = sum;
    __syncthreads();
    for (int off = 1; off < 1024; off <<= 1) {
        int add = (t >= off) ? part[t - off] : 0;
        __syncthreads();
        part[t] += add;
        __syncthreads();
    }
    int run = (t == 0) ? 0 : part[t - 1];
    for (int k = 0; k < CH; ++k) {
        int idx = base + k;
        if (idx < N) {
            offsets[idx] = run;
            cursor[idx] = run;
            run += counts[idx];
        }
    }
    if (t == 1023) offsets[N] = part[1023];
}

__global__ __launch_bounds__(256) void fill_kernel(const int* __restrict__ idx_i,
                                                   int* __restrict__ cursor,
                                                   int* __restrict__ csr, int P) {
    int p = blockIdx.x * 256 + threadIdx.x;
    if (p < P) {
        int pos = atomicAdd(&cursor[idx_i[p]], 1);
        csr[pos] = p;
    }
}

// One wave per atom. Each lane owns features {lane, lane+64}; walks the CSR
// segment, recomputes the 20->128 filter on the fly (Wf rows in 40 VGPRs),
// accumulates in registers, one coalesced 512B store. Zero f32 atomics.
__global__ __launch_bounds__(64) void gather_kernel(
    const float* __restrict__ f_ij, const int* __restrict__ idx_j,
    const float* __restrict__ rcut, const float* __restrict__ Wf,
    const float* __restrict__ bf, const float* __restrict__ h,
    const int* __restrict__ offsets, const int* __restrict__ csr,
    float* __restrict__ agg, int N) {
    const int i = blockIdx.x;
    const int lane = threadIdx.x;
    const int f0 = lane, f1 = lane + 64;
    float w0[20], w1[20];
#pragma unroll
    for (int r = 0; r < 20; r += 4) {
        float4 a = *(const float4*)(Wf + f0 * 20 + r);
        float4 b = *(const float4*)(Wf + f1 * 20 + r);
        w0[r] = a.x; w0[r + 1] = a.y; w0[r + 2] = a.z; w0[r + 3] = a.w;
        w1[r] = b.x; w1[r + 1] = b.y; w1[r + 2] = b.z; w1[r + 3] = b.w;
    }
    const float bias0 = bf[f0], bias1 = bf[f1];
    float acc0 = 0.0f, acc1 = 0.0f;
    const int s = offsets[i], e = offsets[i + 1];
    for (int k = s; k < e; ++k) {
        const int p = csr[k];  // wave-uniform
        const float4* fr = (const float4*)(f_ij + (size_t)p * 20);
        float4 q0 = fr[0], q1 = fr[1], q2 = fr[2], q3 = fr[3], q4 = fr[4];
        float fij[20] = {q0.x, q0.y, q0.z, q0.w, q1.x, q1.y, q1.z, q1.w,
                         q2.x, q2.y, q2.z, q2.w, q3.x, q3.y, q3.z, q3.w,
                         q4.x, q4.y, q4.z, q4.w};
        const int jb = idx_j[p] * 128;
        const float rc = rcut[p];
        float a0 = bias0, a1 = bias1;
#pragma unroll
        for (int r = 0; r < 20; ++r) {
            a0 = fmaf(fij[r], w0[r], a0);
            a1 = fmaf(fij[r], w1[r], a1);
        }
        acc0 = fmaf(h[jb + f0], sspf(a0) * rc, acc0);
        acc1 = fmaf(h[jb + f1], sspf(a1) * rc, acc1);
    }
    agg[(size_t)i * 128 + f0] = acc0;
    agg[(size_t)i * 128 + f1] = acc1;
}

extern "C" void kernel_launch(void* const* d_in, const int* in_sizes, int n_in,
                              void* d_out, int out_size, void* d_ws, size_t ws_size,
                              hipStream_t stream) {
    const float* x     = (const float*)d_in[0];
    const float* f_ij  = (const float*)d_in[1];
    const int*   idx_i = (const int*)d_in[2];
    const int*   idx_j = (const int*)d_in[3];
    const float* rcut  = (const float*)d_in[4];
    const float* W_in  = (const float*)d_in[5];
    const float* b_in  = (const float*)d_in[6];
    const float* W_f   = (const float*)d_in[7];
    const float* b_f   = (const float*)d_in[8];
    const float* W_out = (const float*)d_in[9];
    const float* b_out = (const float*)d_in[10];

    const int N = in_sizes[0] / 128;  // 50000 atoms
    const int P = in_sizes[2];        // 1600000 edges

    // workspace layout
    char* ws = (char*)d_ws;
    int* counts  = (int*)ws;                          ws += ((size_t)N + 64) * 4;
    int* offsets = (int*)ws;                          ws += ((size_t)N + 64) * 4;
    int* cursor  = (int*)ws;                          ws += ((size_t)N + 64) * 4;
    int* csr     = (int*)ws;                          ws += (size_t)P * 4;
    float* agg   = (float*)ws;

    float* h = (float*)d_out;  // consumed by gather before final GEMM overwrites

    const int mblocks = (N + 63) / 64;
    gemm128<false><<<mblocks, 256, 0, stream>>>(x, W_in, b_in, h, N);

    hipMemsetAsync(counts, 0, (size_t)N * 4, stream);
    count_kernel<<<(P + 255) / 256, 256, 0, stream>>>(idx_i, counts, P);
    scan_kernel<<<1, 1024, 0, stream>>>(counts, offsets, cursor, N);
    fill_kernel<<<(P + 255) / 256, 256, 0, stream>>>(idx_i, cursor, csr, P);
    gather_kernel<<<N, 64, 0, stream>>>(f_ij, idx_j, rcut, W_f, b_f, h,
                                        offsets, csr, agg, N);

    gemm128<true><<<mblocks, 256, 0, stream>>>(agg, W_out, b_out, (float*)d_out, N);
}

// Round 3
// 1009.881 us; speedup vs baseline: 10.4186x; 1.0256x over previous
//
#include <hip/hip_runtime.h>
#include <hip/hip_bf16.h>

static constexpr float kLog2 = 0.6931471805599453f;

// shifted softplus: softplus(x) - log(2), numerically stable
__device__ __forceinline__ float sspf(float x) {
    return fmaxf(x, 0.0f) + __logf(1.0f + __expf(-fabsf(x))) - kLog2;
}

// C[m][f] = act(bias[f] + sum_k A[m][k] * B[f][k])
// A: [M][128] row-major, B: [128][128] row-major (row = output channel, col = k)
template <bool ACT>
__device__ __forceinline__ void gemm128_body(const float* __restrict__ A,
                                             const float* __restrict__ B,
                                             const float* __restrict__ bias,
                                             float* __restrict__ C, int M,
                                             int blockid) {
    __shared__ float As[64][68];
    __shared__ float Bs[128][68];
    const int tid = threadIdx.x;
    const int rowbase = blockid * 64;
    const int fx = tid & 15;
    const int ax = tid >> 4;
    float acc[4][8];
#pragma unroll
    for (int i = 0; i < 4; ++i)
#pragma unroll
        for (int j = 0; j < 8; ++j) acc[i][j] = 0.0f;

    for (int k0 = 0; k0 < 128; k0 += 64) {
#pragma unroll
        for (int it = 0; it < 4; ++it) {
            int idx = it * 256 + tid;
            int r = idx >> 4, c = (idx & 15) << 2;
            int rg = rowbase + r;
            rg = rg < M ? rg : (M - 1);
            *(float4*)&As[r][c] = *(const float4*)(A + (size_t)rg * 128 + k0 + c);
        }
#pragma unroll
        for (int it = 0; it < 8; ++it) {
            int idx = it * 256 + tid;
            int r = idx >> 4, c = (idx & 15) << 2;
            *(float4*)&Bs[r][c] = *(const float4*)(B + (size_t)r * 128 + k0 + c);
        }
        __syncthreads();
#pragma unroll
        for (int kk = 0; kk < 64; kk += 4) {
            float4 av[4], bv[8];
#pragma unroll
            for (int i = 0; i < 4; ++i) av[i] = *(const float4*)&As[ax * 4 + i][kk];
#pragma unroll
            for (int j = 0; j < 8; ++j) bv[j] = *(const float4*)&Bs[fx + j * 16][kk];
#pragma unroll
            for (int i = 0; i < 4; ++i)
#pragma unroll
                for (int j = 0; j < 8; ++j) {
                    acc[i][j] = fmaf(av[i].x, bv[j].x, acc[i][j]);
                    acc[i][j] = fmaf(av[i].y, bv[j].y, acc[i][j]);
                    acc[i][j] = fmaf(av[i].z, bv[j].z, acc[i][j]);
                    acc[i][j] = fmaf(av[i].w, bv[j].w, acc[i][j]);
                }
        }
        __syncthreads();
    }
#pragma unroll
    for (int i = 0; i < 4; ++i) {
        int rg = rowbase + ax * 4 + i;
        if (rg < M) {
#pragma unroll
            for (int j = 0; j < 8; ++j) {
                int f = fx + j * 16;
                float v = acc[i][j] + bias[f];
                if (ACT) v = sspf(v);
                C[(size_t)rg * 128 + f] = v;
            }
        }
    }
}

// gemm1 (h = x W_in^T + b_in) fused with count (histogram of idx_i):
// first gemm_blocks blocks do the GEMM tile, the rest grid-stride the count.
// Independent work; overlaps count's memory atomics with gemm's VALU.
__global__ __launch_bounds__(256) void gemm_in_count_kernel(
    const float* __restrict__ A, const float* __restrict__ B,
    const float* __restrict__ bias, float* __restrict__ C, int M,
    const int* __restrict__ idx_i, int* __restrict__ counts, int P,
    int gemm_blocks) {
    if ((int)blockIdx.x < gemm_blocks) {
        gemm128_body<false>(A, B, bias, C, M, blockIdx.x);
    } else {
        const int nthr = (gridDim.x - gemm_blocks) * 256;
        for (int p = (blockIdx.x - gemm_blocks) * 256 + threadIdx.x; p < P;
             p += nthr)
            atomicAdd(&counts[idx_i[p]], 1);
    }
}

__global__ __launch_bounds__(256) void gemm_out_kernel(
    const float* __restrict__ A, const float* __restrict__ B,
    const float* __restrict__ bias, float* __restrict__ C, int M) {
    gemm128_body<true>(A, B, bias, C, M, blockIdx.x);
}

// single-block exclusive scan of counts[0..N) -> offsets[0..N], cursor copy
__global__ __launch_bounds__(1024) void scan_kernel(const int* __restrict__ counts,
                                                    int* __restrict__ offsets,
                                                    int* __restrict__ cursor, int N) {
    __shared__ int part[1024];
    const int t = threadIdx.x;
    const int CH = (N + 1023) / 1024;
    const int base = t * CH;
    int sum = 0;
    for (int k = 0; k < CH; ++k) {
        int idx = base + k;
        if (idx < N) sum += counts[idx];
    }
    part[t] = sum;
    __syncthreads();
    for (int off = 1; off < 1024; off <<= 1) {
        int add = (t >= off) ? part[t - off] : 0;
        __syncthreads();
        part[t] += add;
        __syncthreads();
    }
    int run = (t == 0) ? 0 : part[t - 1];
    for (int k = 0; k < CH; ++k) {
        int idx = base + k;
        if (idx < N) {
            offsets[idx] = run;
            cursor[idx] = run;
            run += counts[idx];
        }
    }
    if (t == 1023) offsets[N] = part[1023];
}

__global__ __launch_bounds__(256) void fill_kernel(const int* __restrict__ idx_i,
                                                   int* __restrict__ cursor,
                                                   int* __restrict__ csr, int P) {
    int p = blockIdx.x * 256 + threadIdx.x;
    if (p < P) {
        int pos = atomicAdd(&cursor[idx_i[p]], 1);
        csr[pos] = p;
    }
}

// 4 waves/block, grid-stride over atoms (one wave per atom segment).
// Lane owns features {2*lane, 2*lane+1}. All per-edge wave-uniform data
// (csr id, f_ij row, idx_j, rcut) is forced through SGPRs / s_load via
// readfirstlane -> scalar pipe, freeing the vector pipe for the 40 FMAs.
__global__ __launch_bounds__(256) void gather_kernel(
    const float* __restrict__ f_ij, const int* __restrict__ idx_j,
    const float* __restrict__ rcut, const float* __restrict__ Wf,
    const float* __restrict__ bf, const float* __restrict__ h,
    const int* __restrict__ offsets, const int* __restrict__ csr,
    float* __restrict__ agg, int N) {
    const int lane = threadIdx.x & 63;
    const int gwave = (blockIdx.x * 256 + threadIdx.x) >> 6;
    const int nwaves = (gridDim.x * 256) >> 6;
    const int f0 = lane * 2;

    // per-wave-lifetime prologue: 2 adjacent W_filter rows -> 40 VGPRs
    float w0[20], w1[20];
    const float* wrow = Wf + f0 * 20;
#pragma unroll
    for (int r = 0; r < 20; r += 4) {
        float4 a = *(const float4*)(wrow + r);
        float4 b = *(const float4*)(wrow + 20 + r);
        w0[r] = a.x; w0[r + 1] = a.y; w0[r + 2] = a.z; w0[r + 3] = a.w;
        w1[r] = b.x; w1[r + 1] = b.y; w1[r + 2] = b.z; w1[r + 3] = b.w;
    }
    const float2 bias = *(const float2*)(bf + f0);

    for (int i = gwave; i < N; i += nwaves) {
        const int s = __builtin_amdgcn_readfirstlane(offsets[i]);
        const int e = __builtin_amdgcn_readfirstlane(offsets[i + 1]);
        float acc0 = 0.0f, acc1 = 0.0f;
        for (int k = s; k < e; ++k) {
            const int p = __builtin_amdgcn_readfirstlane(csr[k]);
            const float* fr = f_ij + (size_t)p * 20;  // uniform addr -> s_load
            const int jb = __builtin_amdgcn_readfirstlane(idx_j[p]) * 128;
            const float rc = rcut[p];
            float a0 = bias.x, a1 = bias.y;
#pragma unroll
            for (int r = 0; r < 20; ++r) {
                const float fv = fr[r];
                a0 = fmaf(fv, w0[r], a0);
                a1 = fmaf(fv, w1[r], a1);
            }
            const float2 hv = *(const float2*)(h + jb + f0);
            acc0 = fmaf(hv.x, sspf(a0) * rc, acc0);
            acc1 = fmaf(hv.y, sspf(a1) * rc, acc1);
        }
        *(float2*)(agg + (size_t)i * 128 + f0) = make_float2(acc0, acc1);
    }
}

extern "C" void kernel_launch(void* const* d_in, const int* in_sizes, int n_in,
                              void* d_out, int out_size, void* d_ws, size_t ws_size,
                              hipStream_t stream) {
    const float* x     = (const float*)d_in[0];
    const float* f_ij  = (const float*)d_in[1];
    const int*   idx_i = (const int*)d_in[2];
    const int*   idx_j = (const int*)d_in[3];
    const float* rcut  = (const float*)d_in[4];
    const float* W_in  = (const float*)d_in[5];
    const float* b_in  = (const float*)d_in[6];
    const float* W_f   = (const float*)d_in[7];
    const float* b_f   = (const float*)d_in[8];
    const float* W_out = (const float*)d_in[9];
    const float* b_out = (const float*)d_in[10];

    const int N = in_sizes[0] / 128;  // 50000 atoms
    const int P = in_sizes[2];        // 1600000 edges

    // workspace layout
    char* ws = (char*)d_ws;
    int* counts  = (int*)ws;                          ws += ((size_t)N + 64) * 4;
    int* offsets = (int*)ws;                          ws += ((size_t)N + 64) * 4;
    int* cursor  = (int*)ws;                          ws += ((size_t)N + 64) * 4;
    int* csr     = (int*)ws;                          ws += (size_t)P * 4;
    float* agg   = (float*)ws;

    float* h = (float*)d_out;  // consumed by gather before final GEMM overwrites

    const int mblocks = (N + 63) / 64;      // 782 gemm tiles
    const int cblocks = 1024;               // count blocks (grid-stride)

    hipMemsetAsync(counts, 0, (size_t)N * 4, stream);
    gemm_in_count_kernel<<<mblocks + cblocks, 256, 0, stream>>>(
        x, W_in, b_in, h, N, idx_i, counts, P, mblocks);
    scan_kernel<<<1, 1024, 0, stream>>>(counts, offsets, cursor, N);
    fill_kernel<<<(P + 255) / 256, 256, 0, stream>>>(idx_i, cursor, csr, P);
    gather_kernel<<<2048, 256, 0, stream>>>(f_ij, idx_j, rcut, W_f, b_f, h,
                                            offsets, csr, agg, N);
    gemm_out_kernel<<<mblocks, 256, 0, stream>>>(agg, W_out, b_out, (float*)d_out, N);
}

// Round 4
// 879.813 us; speedup vs baseline: 11.9589x; 1.1478x over previous
//
#include <hip/hip_runtime.h>
#include <hip/hip_bf16.h>

static constexpr float kLog2 = 0.6931471805599453f;

__device__ __forceinline__ float sspf(float x) {
    return fmaxf(x, 0.0f) + __logf(1.0f + __expf(-fabsf(x))) - kLog2;
}

typedef __attribute__((ext_vector_type(8))) _Float16 half8;
typedef __attribute__((ext_vector_type(4))) _Float16 half4v;
typedef __attribute__((ext_vector_type(4))) float float4v;

// C[m][f] = act(bias[f] + sum_k A[m][k]*B[f][k]), A:[M][128] f32, B:[128][128] f32.
// f16 MFMA 16x16x32. Whole K resident in LDS (one staging pass, no K-loop over
// global). Row pad 136 halves -> frag ds_read_b128 lands 2-way (free).
// A-frag: lane holds A[m=lane&15][k=q*8+j]; B-frag: B[n=lane&15][k=q*8+j];
// D: row=q*4+r, col=lane&15  (gfx950 verified layouts).
template <bool ACT>
__device__ __forceinline__ void gemm_mfma_body(const float* __restrict__ A,
                                               const float* __restrict__ B,
                                               const float* __restrict__ bias,
                                               float* __restrict__ C, int M,
                                               int blockid) {
    constexpr int LDH = 136;
    __shared__ _Float16 Als[64 * LDH];
    __shared__ _Float16 Bls[128 * LDH];
    const int tid = threadIdx.x;
    const int rowbase = blockid * 64;
#pragma unroll
    for (int j = 0; j < 8; ++j) {  // A: 64x128 f32 -> f16 LDS
        int idx = j * 256 + tid;
        int r = idx >> 5, c4 = (idx & 31) << 2;
        int rg = rowbase + r;
        rg = rg < M ? rg : (M - 1);
        float4 v = *(const float4*)(A + (size_t)rg * 128 + c4);
        half4v hv = {(_Float16)v.x, (_Float16)v.y, (_Float16)v.z, (_Float16)v.w};
        *(half4v*)&Als[r * LDH + c4] = hv;
    }
#pragma unroll
    for (int j = 0; j < 16; ++j) {  // B: 128x128 f32 -> f16 LDS
        int idx = j * 256 + tid;
        int r = idx >> 5, c4 = (idx & 31) << 2;
        float4 v = *(const float4*)(B + (size_t)r * 128 + c4);
        half4v hv = {(_Float16)v.x, (_Float16)v.y, (_Float16)v.z, (_Float16)v.w};
        *(half4v*)&Bls[r * LDH + c4] = hv;
    }
    __syncthreads();

    const int wave = tid >> 6, lane = tid & 63;
    const int l15 = lane & 15, q = lane >> 4;
    float4v acc[8];
#pragma unroll
    for (int nt = 0; nt < 8; ++nt) acc[nt] = (float4v){0.f, 0.f, 0.f, 0.f};
    const int am = wave * 16 + l15;
#pragma unroll
    for (int kk = 0; kk < 4; ++kk) {
        half8 af = *(const half8*)&Als[am * LDH + kk * 32 + q * 8];
#pragma unroll
        for (int nt = 0; nt < 8; ++nt) {
            half8 bf = *(const half8*)&Bls[(nt * 16 + l15) * LDH + kk * 32 + q * 8];
            acc[nt] = __builtin_amdgcn_mfma_f32_16x16x32_f16(af, bf, acc[nt], 0, 0, 0);
        }
    }
#pragma unroll
    for (int nt = 0; nt < 8; ++nt) {
        int n = nt * 16 + l15;
        float bv = bias[n];
#pragma unroll
        for (int r = 0; r < 4; ++r) {
            int m = rowbase + wave * 16 + q * 4 + r;
            if (m < M) {
                float v = acc[nt][r] + bv;
                if (ACT) v = sspf(v);
                C[(size_t)m * 128 + n] = v;
            }
        }
    }
}

// gemm1 (h = x W_in^T + b_in) fused with idx_i histogram (independent work).
__global__ __launch_bounds__(256) void gemm_in_count_kernel(
    const float* __restrict__ A, const float* __restrict__ B,
    const float* __restrict__ bias, float* __restrict__ C, int M,
    const int* __restrict__ idx_i, int* __restrict__ counts, int P,
    int gemm_blocks) {
    if ((int)blockIdx.x < gemm_blocks) {
        gemm_mfma_body<false>(A, B, bias, C, M, blockIdx.x);
    } else {
        const int nthr = (gridDim.x - gemm_blocks) * 256;
        for (int p = (blockIdx.x - gemm_blocks) * 256 + threadIdx.x; p < P;
             p += nthr)
            atomicAdd(&counts[idx_i[p]], 1);
    }
}

__global__ __launch_bounds__(256) void gemm_out_kernel(
    const float* __restrict__ A, const float* __restrict__ B,
    const float* __restrict__ bias, float* __restrict__ C, int M) {
    gemm_mfma_body<true>(A, B, bias, C, M, blockIdx.x);
}

// single-block exclusive scan of counts[0..N) -> offsets[0..N], cursor copy
__global__ __launch_bounds__(1024) void scan_kernel(const int* __restrict__ counts,
                                                    int* __restrict__ offsets,
                                                    int* __restrict__ cursor, int N) {
    __shared__ int part[1024];
    const int t = threadIdx.x;
    const int CH = (N + 1023) / 1024;
    const int base = t * CH;
    int sum = 0;
    for (int k = 0; k < CH; ++k) {
        int idx = base + k;
        if (idx < N) sum += counts[idx];
    }
    part[t] = sum;
    __syncthreads();
    for (int off = 1; off < 1024; off <<= 1) {
        int add = (t >= off) ? part[t - off] : 0;
        __syncthreads();
        part[t] += add;
        __syncthreads();
    }
    int run = (t == 0) ? 0 : part[t - 1];
    for (int k = 0; k < CH; ++k) {
        int idx = base + k;
        if (idx < N) {
            offsets[idx] = run;
            cursor[idx] = run;
            run += counts[idx];
        }
    }
    if (t == 1023) offsets[N] = part[1023];
}

__global__ __launch_bounds__(256) void fill_kernel(const int* __restrict__ idx_i,
                                                   int* __restrict__ cursor,
                                                   int* __restrict__ csr, int P) {
    int p = blockIdx.x * 256 + threadIdx.x;
    if (p < P) {
        int pos = atomicAdd(&cursor[idx_i[p]], 1);
        csr[pos] = p;
    }
}

// One wave per atom segment, grid-stride. Per 64-edge chunk: ONE coalesced
// lane-parallel load of csr/idx_j/rcut, then per-edge broadcast via
// v_readlane (no memory). Per edge: uniform f_ij s_load + float2 h load +
// 40 filter FMAs. Lane owns features {2*lane, 2*lane+1}.
__global__ __launch_bounds__(256) void gather_kernel(
    const float* __restrict__ f_ij, const int* __restrict__ idx_j,
    const float* __restrict__ rcut, const float* __restrict__ Wf,
    const float* __restrict__ bf, const float* __restrict__ h,
    const int* __restrict__ offsets, const int* __restrict__ csr,
    float* __restrict__ agg, int N) {
    const int lane = threadIdx.x & 63;
    const int gwave = (blockIdx.x * 256 + threadIdx.x) >> 6;
    const int nwaves = (gridDim.x * 256) >> 6;
    const int f0 = lane * 2;

    float w0[20], w1[20];
    const float* wrow = Wf + f0 * 20;
#pragma unroll
    for (int r = 0; r < 20; r += 4) {
        float4 a = *(const float4*)(wrow + r);
        float4 b = *(const float4*)(wrow + 20 + r);
        w0[r] = a.x; w0[r + 1] = a.y; w0[r + 2] = a.z; w0[r + 3] = a.w;
        w1[r] = b.x; w1[r + 1] = b.y; w1[r + 2] = b.z; w1[r + 3] = b.w;
    }
    const float2 bias = *(const float2*)(bf + f0);

    for (int i = gwave; i < N; i += nwaves) {
        const int s = __builtin_amdgcn_readfirstlane(offsets[i]);
        const int e = __builtin_amdgcn_readfirstlane(offsets[i + 1]);
        float acc0 = 0.0f, acc1 = 0.0f;
        for (int c = s; c < e; c += 64) {
            const int cnt = min(64, e - c);
            int vp = 0, vjb = 0, vrc = 0;
            if (c + lane < e) {
                vp = csr[c + lane];
                vjb = idx_j[vp];
                vrc = __float_as_int(rcut[vp]);
            }
#pragma unroll 2
            for (int k = 0; k < cnt; ++k) {
                const int p = __builtin_amdgcn_readlane(vp, k);
                const int jb = __builtin_amdgcn_readlane(vjb, k) << 7;
                const float rc = __int_as_float(__builtin_amdgcn_readlane(vrc, k));
                const float2 hv = *(const float2*)(h + jb + f0);  // issue early
                const float* fr = f_ij + (size_t)p * 20;  // SGPR-uniform -> s_load
                float a0 = bias.x, a1 = bias.y;
#pragma unroll
                for (int r = 0; r < 20; ++r) {
                    const float fv = fr[r];
                    a0 = fmaf(fv, w0[r], a0);
                    a1 = fmaf(fv, w1[r], a1);
                }
                acc0 = fmaf(hv.x, sspf(a0) * rc, acc0);
                acc1 = fmaf(hv.y, sspf(a1) * rc, acc1);
            }
        }
        *(float2*)(agg + (size_t)i * 128 + f0) = make_float2(acc0, acc1);
    }
}

extern "C" void kernel_launch(void* const* d_in, const int* in_sizes, int n_in,
                              void* d_out, int out_size, void* d_ws, size_t ws_size,
                              hipStream_t stream) {
    const float* x     = (const float*)d_in[0];
    const float* f_ij  = (const float*)d_in[1];
    const int*   idx_i = (const int*)d_in[2];
    const int*   idx_j = (const int*)d_in[3];
    const float* rcut  = (const float*)d_in[4];
    const float* W_in  = (const float*)d_in[5];
    const float* b_in  = (const float*)d_in[6];
    const float* W_f   = (const float*)d_in[7];
    const float* b_f   = (const float*)d_in[8];
    const float* W_out = (const float*)d_in[9];
    const float* b_out = (const float*)d_in[10];

    const int N = in_sizes[0] / 128;  // 50000 atoms
    const int P = in_sizes[2];        // 1600000 edges

    char* ws = (char*)d_ws;
    int* counts  = (int*)ws;                          ws += ((size_t)N + 64) * 4;
    int* offsets = (int*)ws;                          ws += ((size_t)N + 64) * 4;
    int* cursor  = (int*)ws;                          ws += ((size_t)N + 64) * 4;
    int* csr     = (int*)ws;                          ws += (size_t)P * 4;
    float* agg   = (float*)ws;

    float* h = (float*)d_out;  // consumed by gather before gemm_out overwrites

    const int mblocks = (N + 63) / 64;  // 782
    const int cblocks = 1024;

    hipMemsetAsync(counts, 0, (size_t)N * 4, stream);
    gemm_in_count_kernel<<<mblocks + cblocks, 256, 0, stream>>>(
        x, W_in, b_in, h, N, idx_i, counts, P, mblocks);
    scan_kernel<<<1, 1024, 0, stream>>>(counts, offsets, cursor, N);
    fill_kernel<<<(P + 255) / 256, 256, 0, stream>>>(idx_i, cursor, csr, P);
    gather_kernel<<<2048, 256, 0, stream>>>(f_ij, idx_j, rcut, W_f, b_f, h,
                                            offsets, csr, agg, N);
    gemm_out_kernel<<<mblocks, 256, 0, stream>>>(agg, W_out, b_out, (float*)d_out, N);
}

// Round 5
// 765.279 us; speedup vs baseline: 13.7487x; 1.1497x over previous
//
#include <hip/hip_runtime.h>
#include <hip/hip_bf16.h>

static constexpr float kLog2 = 0.6931471805599453f;

__device__ __forceinline__ float sspf(float x) {
    return fmaxf(x, 0.0f) + __logf(1.0f + __expf(-fabsf(x))) - kLog2;
}

typedef __attribute__((ext_vector_type(8))) _Float16 half8;
typedef __attribute__((ext_vector_type(4))) _Float16 half4v;
typedef __attribute__((ext_vector_type(4))) float float4v;

// C[m][f] = act(bias[f] + sum_k A[m][k]*B[f][k]); A:[M][128] f32, B:[128][128] f32.
// f16 MFMA 16x16x32, whole K in LDS. OUT selects f32 or f16 store.
template <bool ACT, typename OUT>
__device__ __forceinline__ void gemm_mfma_body(const float* __restrict__ A,
                                               const float* __restrict__ B,
                                               const float* __restrict__ bias,
                                               OUT* __restrict__ C, int M,
                                               int blockid) {
    constexpr int LDH = 136;
    __shared__ _Float16 Als[64 * LDH];
    __shared__ _Float16 Bls[128 * LDH];
    const int tid = threadIdx.x;
    const int rowbase = blockid * 64;
#pragma unroll
    for (int j = 0; j < 8; ++j) {
        int idx = j * 256 + tid;
        int r = idx >> 5, c4 = (idx & 31) << 2;
        int rg = rowbase + r;
        rg = rg < M ? rg : (M - 1);
        float4 v = *(const float4*)(A + (size_t)rg * 128 + c4);
        half4v hv = {(_Float16)v.x, (_Float16)v.y, (_Float16)v.z, (_Float16)v.w};
        *(half4v*)&Als[r * LDH + c4] = hv;
    }
#pragma unroll
    for (int j = 0; j < 16; ++j) {
        int idx = j * 256 + tid;
        int r = idx >> 5, c4 = (idx & 31) << 2;
        float4 v = *(const float4*)(B + (size_t)r * 128 + c4);
        half4v hv = {(_Float16)v.x, (_Float16)v.y, (_Float16)v.z, (_Float16)v.w};
        *(half4v*)&Bls[r * LDH + c4] = hv;
    }
    __syncthreads();

    const int wave = tid >> 6, lane = tid & 63;
    const int l15 = lane & 15, q = lane >> 4;
    float4v acc[8];
#pragma unroll
    for (int nt = 0; nt < 8; ++nt) acc[nt] = (float4v){0.f, 0.f, 0.f, 0.f};
    const int am = wave * 16 + l15;
#pragma unroll
    for (int kk = 0; kk < 4; ++kk) {
        half8 af = *(const half8*)&Als[am * LDH + kk * 32 + q * 8];
#pragma unroll
        for (int nt = 0; nt < 8; ++nt) {
            half8 bf = *(const half8*)&Bls[(nt * 16 + l15) * LDH + kk * 32 + q * 8];
            acc[nt] = __builtin_amdgcn_mfma_f32_16x16x32_f16(af, bf, acc[nt], 0, 0, 0);
        }
    }
#pragma unroll
    for (int nt = 0; nt < 8; ++nt) {
        int n = nt * 16 + l15;
        float bv = bias[n];
#pragma unroll
        for (int r = 0; r < 4; ++r) {
            int m = rowbase + wave * 16 + q * 4 + r;
            if (m < M) {
                float v = acc[nt][r] + bv;
                if (ACT) v = sspf(v);
                C[(size_t)m * 128 + n] = (OUT)v;
            }
        }
    }
}

// gemm1 (h16 = f16(x W_in^T + b_in)) fused with idx_i histogram.
__global__ __launch_bounds__(256) void gemm_in_count_kernel(
    const float* __restrict__ A, const float* __restrict__ B,
    const float* __restrict__ bias, _Float16* __restrict__ C, int M,
    const int* __restrict__ idx_i, int* __restrict__ counts, int P,
    int gemm_blocks) {
    if ((int)blockIdx.x < gemm_blocks) {
        gemm_mfma_body<false, _Float16>(A, B, bias, C, M, blockIdx.x);
    } else {
        const int nthr = (gridDim.x - gemm_blocks) * 256;
        for (int p = (blockIdx.x - gemm_blocks) * 256 + threadIdx.x; p < P;
             p += nthr)
            atomicAdd(&counts[idx_i[p]], 1);
    }
}

// out = ssp(agg W_out^T + b_out), IN-PLACE on d_out (tile staged to LDS first).
__global__ __launch_bounds__(256) void gemm_out_kernel(
    const float* __restrict__ A, const float* __restrict__ B,
    const float* __restrict__ bias, float* __restrict__ C, int M) {
    gemm_mfma_body<true, float>(A, B, bias, C, M, blockIdx.x);
}

// ---- parallel CSR prefix: block sums -> scan partials -> write offsets ----
__global__ __launch_bounds__(256) void block_sums_kernel(
    const int* __restrict__ counts, int* __restrict__ partials, int N) {
    __shared__ int red[256];
    int t = threadIdx.x, g = blockIdx.x * 256 + t;
    red[t] = g < N ? counts[g] : 0;
    __syncthreads();
    for (int o = 128; o > 0; o >>= 1) {
        if (t < o) red[t] += red[t + o];
        __syncthreads();
    }
    if (t == 0) partials[blockIdx.x] = red[0];
}

__global__ __launch_bounds__(256) void scan_partials_kernel(int* __restrict__ partials,
                                                            int NB) {
    __shared__ int s[256];
    int t = threadIdx.x;
    s[t] = t < NB ? partials[t] : 0;
    __syncthreads();
    for (int o = 1; o < 256; o <<= 1) {
        int v = t >= o ? s[t - o] : 0;
        __syncthreads();
        s[t] += v;
        __syncthreads();
    }
    partials[t] = t ? s[t - 1] : 0;  // exclusive
}

__global__ __launch_bounds__(256) void write_offsets_kernel(
    const int* __restrict__ counts, const int* __restrict__ partials,
    int* __restrict__ offsets, int* __restrict__ cursor, int N) {
    __shared__ int s[256];
    int t = threadIdx.x, g = blockIdx.x * 256 + t;
    int c = g < N ? counts[g] : 0;
    s[t] = c;
    __syncthreads();
    for (int o = 1; o < 256; o <<= 1) {
        int v = t >= o ? s[t - o] : 0;
        __syncthreads();
        s[t] += v;
        __syncthreads();
    }
    int excl = partials[blockIdx.x] + s[t] - c;
    if (g < N) {
        offsets[g] = excl;
        cursor[g] = excl;
        if (g == N - 1) offsets[N] = excl + c;
    }
}

__global__ __launch_bounds__(256) void fill_kernel(const int* __restrict__ idx_i,
                                                   int* __restrict__ cursor,
                                                   int* __restrict__ csr, int P) {
    int p = blockIdx.x * 256 + threadIdx.x;
    if (p < P) {
        int pos = atomicAdd(&cursor[idx_i[p]], 1);
        csr[pos] = p;
    }
}

// One wave per atom segment, 16 edges per MFMA group.
// Lane (q,l15): supplies A = W_filter rows (features nt*16+l15, preloaded, bias
// folded at k=20) and B = edge l15's f_ij row (k padded 20->32, B[k=20]=1).
// D[nt][r] = raw filter for feature nt*16+q*4+r, edge l15. Lane then loads
// h16[j_{l15}] half4s for ITS edge, acc += ssp(D)*rc*h. Segment-sum finishes
// with a 4-step shfl_xor over the l15 (edge) dimension.
__global__ __launch_bounds__(256) void gather_mfma_kernel(
    const float* __restrict__ f_ij, const int* __restrict__ idx_j,
    const float* __restrict__ rcut, const float* __restrict__ Wf,
    const float* __restrict__ bf, const _Float16* __restrict__ h16,
    const int* __restrict__ offsets, const int* __restrict__ csr,
    float* __restrict__ agg, int N) {
    const int lane = threadIdx.x & 63;
    const int gwave = (blockIdx.x * 256 + threadIdx.x) >> 6;
    const int nwaves = (gridDim.x * 256) >> 6;
    const int l15 = lane & 15, q = lane >> 4;

    // A-fragments: W_filter, A[m=l15][k=q*8+j], bias at k==20, zero k>20.
    half8 wfr[8];
#pragma unroll
    for (int nt = 0; nt < 8; ++nt) {
        const float* wr = Wf + (size_t)(nt * 16 + l15) * 20;
        float v[8];
#pragma unroll
        for (int j = 0; j < 8; ++j) {
            int k = q * 8 + j;
            v[j] = (k < 20) ? wr[k] : ((k == 20) ? bf[nt * 16 + l15] : 0.0f);
        }
        wfr[nt] = (half8){(_Float16)v[0], (_Float16)v[1], (_Float16)v[2],
                          (_Float16)v[3], (_Float16)v[4], (_Float16)v[5],
                          (_Float16)v[6], (_Float16)v[7]};
    }
    const float4v zero = {0.f, 0.f, 0.f, 0.f};

    for (int i = gwave; i < N; i += nwaves) {
        const int s = __builtin_amdgcn_readfirstlane(offsets[i]);
        const int e = __builtin_amdgcn_readfirstlane(offsets[i + 1]);
        float4v acc[8];
#pragma unroll
        for (int nt = 0; nt < 8; ++nt) acc[nt] = zero;

        for (int c = s; c < e; c += 16) {
            const int k = c + l15;
            const int pidx = k < e ? k : (e - 1);
            const int p = csr[pidx];              // lane's edge (valid clamp)
            const int jb = idx_j[p] << 7;
            const float rc = (k < e) ? rcut[p] : 0.0f;  // kills tail lanes
            const float* fp = f_ij + (size_t)p * 20;
            // B-fragment: edge f_ij, k = q*8+j, pad: B[20]=1.0, B[>20]=0.
            float b0 = 0.f, b1 = 0.f, b2 = 0.f, b3 = 0.f;
            float b4 = 0.f, b5 = 0.f, b6 = 0.f, b7 = 0.f;
            if (q <= 2) {
                float4 a = *(const float4*)(fp + q * 8);  // q=2 -> k16..19
                b0 = a.x; b1 = a.y; b2 = a.z; b3 = a.w;
            }
            if (q <= 1) {
                float4 bb = *(const float4*)(fp + q * 8 + 4);
                b4 = bb.x; b5 = bb.y; b6 = bb.z; b7 = bb.w;
            }
            if (q == 2) b4 = 1.0f;  // k == 20: bias multiplier
            half8 bfrag = (half8){(_Float16)b0, (_Float16)b1, (_Float16)b2,
                                  (_Float16)b3, (_Float16)b4, (_Float16)b5,
                                  (_Float16)b6, (_Float16)b7};
#pragma unroll
            for (int nt = 0; nt < 8; ++nt) {
                float4v d = __builtin_amdgcn_mfma_f32_16x16x32_f16(wfr[nt], bfrag,
                                                                   zero, 0, 0, 0);
                half4v hv = *(const half4v*)(h16 + jb + nt * 16 + q * 4);
#pragma unroll
                for (int r = 0; r < 4; ++r) {
                    float w = sspf(d[r]) * rc;
                    acc[nt][r] = fmaf(w, (float)hv[r], acc[nt][r]);
                }
            }
        }
        // reduce across the 16-edge (l15) dimension
#pragma unroll
        for (int m = 1; m <= 8; m <<= 1)
#pragma unroll
            for (int nt = 0; nt < 8; ++nt)
#pragma unroll
                for (int r = 0; r < 4; ++r)
                    acc[nt][r] += __shfl_xor(acc[nt][r], m, 64);
        if (l15 == 0) {
#pragma unroll
            for (int nt = 0; nt < 8; ++nt) {
                float4 o = {acc[nt][0], acc[nt][1], acc[nt][2], acc[nt][3]};
                *(float4*)(agg + (size_t)i * 128 + nt * 16 + q * 4) = o;
            }
        }
    }
}

extern "C" void kernel_launch(void* const* d_in, const int* in_sizes, int n_in,
                              void* d_out, int out_size, void* d_ws, size_t ws_size,
                              hipStream_t stream) {
    const float* x     = (const float*)d_in[0];
    const float* f_ij  = (const float*)d_in[1];
    const int*   idx_i = (const int*)d_in[2];
    const int*   idx_j = (const int*)d_in[3];
    const float* rcut  = (const float*)d_in[4];
    const float* W_in  = (const float*)d_in[5];
    const float* b_in  = (const float*)d_in[6];
    const float* W_f   = (const float*)d_in[7];
    const float* b_f   = (const float*)d_in[8];
    const float* W_out = (const float*)d_in[9];
    const float* b_out = (const float*)d_in[10];

    const int N = in_sizes[0] / 128;  // 50000 atoms
    const int P = in_sizes[2];        // 1600000 edges
    const int NB = (N + 255) / 256;   // 196 scan blocks

    char* ws = (char*)d_ws;
    int* counts   = (int*)ws;  ws += ((size_t)N + 64) * 4;
    int* offsets  = (int*)ws;  ws += ((size_t)N + 64) * 4;
    int* cursor   = (int*)ws;  ws += ((size_t)N + 64) * 4;
    int* partials = (int*)ws;  ws += 1024;
    int* csr      = (int*)ws;  ws += (size_t)P * 4;
    _Float16* h16 = (_Float16*)ws;  // N*128*2 = 12.8 MB

    float* agg = (float*)d_out;  // gather writes agg; gemm_out runs in-place

    const int mblocks = (N + 63) / 64;  // 782
    const int cblocks = 768;

    hipMemsetAsync(counts, 0, (size_t)N * 4, stream);
    gemm_in_count_kernel<<<mblocks + cblocks, 256, 0, stream>>>(
        x, W_in, b_in, h16, N, idx_i, counts, P, mblocks);
    block_sums_kernel<<<NB, 256, 0, stream>>>(counts, partials, N);
    scan_partials_kernel<<<1, 256, 0, stream>>>(partials, NB);
    write_offsets_kernel<<<NB, 256, 0, stream>>>(counts, partials, offsets, cursor, N);
    fill_kernel<<<(P + 255) / 256, 256, 0, stream>>>(idx_i, cursor, csr, P);
    gather_mfma_kernel<<<2048, 256, 0, stream>>>(f_ij, idx_j, rcut, W_f, b_f,
                                                 h16, offsets, csr, agg, N);
    gemm_out_kernel<<<mblocks, 256, 0, stream>>>(agg, W_out, b_out, (float*)d_out, N);
}

// Round 6
// 628.427 us; speedup vs baseline: 16.7428x; 1.2178x over previous
//
#include <hip/hip_runtime.h>
#include <hip/hip_bf16.h>

static constexpr float kLog2 = 0.6931471805599453f;

__device__ __forceinline__ float sspf(float x) {
    return fmaxf(x, 0.0f) + __logf(1.0f + __expf(-fabsf(x))) - kLog2;
}

typedef __attribute__((ext_vector_type(8))) _Float16 half8;
typedef __attribute__((ext_vector_type(4))) _Float16 half4v;
typedef __attribute__((ext_vector_type(4))) float float4v;

// ---------------- dense GEMMs (f16 MFMA 16x16x32, whole K in LDS) ----------
template <bool ACT, typename OUT>
__device__ __forceinline__ void gemm_mfma_body(const float* __restrict__ A,
                                               const float* __restrict__ B,
                                               const float* __restrict__ bias,
                                               OUT* __restrict__ C, int M,
                                               int blockid) {
    constexpr int LDH = 136;
    __shared__ _Float16 Als[64 * LDH];
    __shared__ _Float16 Bls[128 * LDH];
    const int tid = threadIdx.x;
    const int rowbase = blockid * 64;
#pragma unroll
    for (int j = 0; j < 8; ++j) {
        int idx = j * 256 + tid;
        int r = idx >> 5, c4 = (idx & 31) << 2;
        int rg = rowbase + r;
        rg = rg < M ? rg : (M - 1);
        float4 v = *(const float4*)(A + (size_t)rg * 128 + c4);
        half4v hv = {(_Float16)v.x, (_Float16)v.y, (_Float16)v.z, (_Float16)v.w};
        *(half4v*)&Als[r * LDH + c4] = hv;
    }
#pragma unroll
    for (int j = 0; j < 16; ++j) {
        int idx = j * 256 + tid;
        int r = idx >> 5, c4 = (idx & 31) << 2;
        float4 v = *(const float4*)(B + (size_t)r * 128 + c4);
        half4v hv = {(_Float16)v.x, (_Float16)v.y, (_Float16)v.z, (_Float16)v.w};
        *(half4v*)&Bls[r * LDH + c4] = hv;
    }
    __syncthreads();

    const int wave = tid >> 6, lane = tid & 63;
    const int l15 = lane & 15, q = lane >> 4;
    float4v acc[8];
#pragma unroll
    for (int nt = 0; nt < 8; ++nt) acc[nt] = (float4v){0.f, 0.f, 0.f, 0.f};
    const int am = wave * 16 + l15;
#pragma unroll
    for (int kk = 0; kk < 4; ++kk) {
        half8 af = *(const half8*)&Als[am * LDH + kk * 32 + q * 8];
#pragma unroll
        for (int nt = 0; nt < 8; ++nt) {
            half8 bfv = *(const half8*)&Bls[(nt * 16 + l15) * LDH + kk * 32 + q * 8];
            acc[nt] = __builtin_amdgcn_mfma_f32_16x16x32_f16(af, bfv, acc[nt], 0, 0, 0);
        }
    }
#pragma unroll
    for (int nt = 0; nt < 8; ++nt) {
        int n = nt * 16 + l15;
        float bv = bias[n];
#pragma unroll
        for (int r = 0; r < 4; ++r) {
            int m = rowbase + wave * 16 + q * 4 + r;
            if (m < M) {
                float v = acc[nt][r] + bv;
                if (ACT) v = sspf(v);
                C[(size_t)m * 128 + n] = (OUT)v;
            }
        }
    }
}

__global__ __launch_bounds__(256) void gemm_in_count_kernel(
    const float* __restrict__ A, const float* __restrict__ B,
    const float* __restrict__ bias, _Float16* __restrict__ C, int M,
    const int* __restrict__ idx_i, int* __restrict__ counts, int P,
    int gemm_blocks) {
    if ((int)blockIdx.x < gemm_blocks) {
        gemm_mfma_body<false, _Float16>(A, B, bias, C, M, blockIdx.x);
    } else {
        const int nthr = (gridDim.x - gemm_blocks) * 256;
        for (int p = (blockIdx.x - gemm_blocks) * 256 + threadIdx.x; p < P;
             p += nthr)
            atomicAdd(&counts[idx_i[p]], 1);
    }
}

__global__ __launch_bounds__(256) void gemm_out_kernel(
    const float* __restrict__ A, const float* __restrict__ B,
    const float* __restrict__ bias, float* __restrict__ C, int M) {
    gemm_mfma_body<true, float>(A, B, bias, C, M, blockIdx.x);
}

// ---- one-kernel segment allocation: block scan + global bump (order-free) ----
__global__ __launch_bounds__(256) void alloc_starts_kernel(
    const int* __restrict__ counts, int* __restrict__ starts,
    int* __restrict__ cursor, int* __restrict__ gtot, int N) {
    __shared__ int s[256];
    __shared__ int base;
    const int t = threadIdx.x, g = blockIdx.x * 256 + t;
    const int c = g < N ? counts[g] : 0;
    s[t] = c;
    __syncthreads();
    for (int o = 1; o < 256; o <<= 1) {
        int v = t >= o ? s[t - o] : 0;
        __syncthreads();
        s[t] += v;
        __syncthreads();
    }
    if (t == 255) base = atomicAdd(gtot, s[255]);
    __syncthreads();
    const int excl = base + s[t] - c;
    if (g < N) {
        starts[g] = excl;
        cursor[g] = excl;
    }
}

// ---- fill: scatter edge payload into segment-sorted order ----
// EF path: ef[pos] = 24 f16 {f_ij[0..19], 1.0(bias mult), 0,0,0}; meta = {jb, rc}.
// fallback: pidx[pos] = p (gather re-reads f_ij f32 via indirection).
template <bool EF>
__global__ __launch_bounds__(256) void fill_kernel(
    const int* __restrict__ idx_i, const int* __restrict__ idx_j,
    const float* __restrict__ rcut, const float* __restrict__ f_ij,
    int* __restrict__ cursor, _Float16* __restrict__ ef,
    int2* __restrict__ meta, int* __restrict__ pidx, int P) {
    int p = blockIdx.x * 256 + threadIdx.x;
    if (p >= P) return;
    const int i = idx_i[p];
    const int pos = atomicAdd(&cursor[i], 1);
    meta[pos] = make_int2(idx_j[p] << 7, __float_as_int(rcut[p]));
    if (EF) {
        const float* fr = f_ij + (size_t)p * 20;
        _Float16 hb[24];
#pragma unroll
        for (int r = 0; r < 20; r += 4) {
            float4 v = *(const float4*)(fr + r);
            hb[r] = (_Float16)v.x; hb[r + 1] = (_Float16)v.y;
            hb[r + 2] = (_Float16)v.z; hb[r + 3] = (_Float16)v.w;
        }
        hb[20] = (_Float16)1.0f; hb[21] = (_Float16)0.0f;
        hb[22] = (_Float16)0.0f; hb[23] = (_Float16)0.0f;
        _Float16* dst = ef + (size_t)pos * 24;
        *(half8*)dst = *(half8*)hb;
        *(half8*)(dst + 8) = *(half8*)(hb + 8);
        *(half8*)(dst + 16) = *(half8*)(hb + 16);
    } else {
        pidx[pos] = p;
    }
}

// ---- gather: one wave per atom, 16 edges/MFMA group, linear payload feeds,
//      2-stage software pipeline (next chunk's ef/meta prefetched). ----
template <bool EF>
__global__ __launch_bounds__(256) void gather_mfma_kernel(
    const _Float16* __restrict__ ef, const int2* __restrict__ meta,
    const int* __restrict__ pidx, const float* __restrict__ f_ij,
    const float* __restrict__ Wf, const float* __restrict__ bf,
    const _Float16* __restrict__ h16, const int* __restrict__ starts,
    const int* __restrict__ counts, float* __restrict__ agg, int N) {
    const int lane = threadIdx.x & 63;
    const int gwave = (blockIdx.x * 256 + threadIdx.x) >> 6;
    const int nwaves = (gridDim.x * 256) >> 6;
    const int l15 = lane & 15, q = lane >> 4;

    // A-fragments: W_filter rows (feature m=l15 within tile nt), bias at k=20.
    half8 wfr[8];
#pragma unroll
    for (int nt = 0; nt < 8; ++nt) {
        const float* wr = Wf + (size_t)(nt * 16 + l15) * 20;
        float v[8];
#pragma unroll
        for (int j = 0; j < 8; ++j) {
            int k = q * 8 + j;
            v[j] = (k < 20) ? wr[k] : ((k == 20) ? bf[nt * 16 + l15] : 0.0f);
        }
        wfr[nt] = (half8){(_Float16)v[0], (_Float16)v[1], (_Float16)v[2],
                          (_Float16)v[3], (_Float16)v[4], (_Float16)v[5],
                          (_Float16)v[6], (_Float16)v[7]};
    }
    const float4v zero = {0.f, 0.f, 0.f, 0.f};

    for (int i = gwave; i < N; i += nwaves) {
        const int s = __builtin_amdgcn_readfirstlane(starts[i]);
        const int cnt = __builtin_amdgcn_readfirstlane(counts[i]);
        const int e = s + cnt;
        float4v acc[8];
#pragma unroll
        for (int nt = 0; nt < 8; ++nt) acc[nt] = zero;

        if (cnt > 0) {
            // prefetch stage for chunk c = s
            int pos = min(s + l15, e - 1);
            half8 bf_n = {};
            if (EF) {
                if (q < 3) bf_n = *(const half8*)(ef + (size_t)pos * 24 + q * 8);
            }
            int2 mt_n = meta[pos];
            int p_n = EF ? 0 : pidx[pos];

            for (int c = s; c < e; c += 16) {
                half8 bf_c = bf_n;
                int2 mt_c = mt_n;
                int p_c = p_n;
                if (c + 16 < e) {  // prefetch next chunk
                    int np = min(c + 16 + l15, e - 1);
                    if (EF) {
                        if (q < 3) bf_n = *(const half8*)(ef + (size_t)np * 24 + q * 8);
                    } else {
                        p_n = pidx[np];
                    }
                    mt_n = meta[np];
                }
                if (!EF) {  // build B-fragment from f32 f_ij (fallback)
                    const float* fp = f_ij + (size_t)p_c * 20;
                    float b0 = 0.f, b1 = 0.f, b2 = 0.f, b3 = 0.f;
                    float b4 = 0.f, b5 = 0.f, b6 = 0.f, b7 = 0.f;
                    if (q <= 2) {
                        float4 a = *(const float4*)(fp + q * 8);
                        b0 = a.x; b1 = a.y; b2 = a.z; b3 = a.w;
                    }
                    if (q <= 1) {
                        float4 bb = *(const float4*)(fp + q * 8 + 4);
                        b4 = bb.x; b5 = bb.y; b6 = bb.z; b7 = bb.w;
                    }
                    if (q == 2) b4 = 1.0f;
                    bf_c = (half8){(_Float16)b0, (_Float16)b1, (_Float16)b2,
                                   (_Float16)b3, (_Float16)b4, (_Float16)b5,
                                   (_Float16)b6, (_Float16)b7};
                }
                const int jb = mt_c.x;  // idx_j*128, lane's own edge (l15)
                const float rc = (c + l15 < e) ? __int_as_float(mt_c.y) : 0.0f;
                half4v hv[8];
#pragma unroll
                for (int nt = 0; nt < 8; ++nt)
                    hv[nt] = *(const half4v*)(h16 + jb + nt * 16 + q * 4);
#pragma unroll
                for (int nt = 0; nt < 8; ++nt) {
                    float4v d = __builtin_amdgcn_mfma_f32_16x16x32_f16(
                        wfr[nt], bf_c, zero, 0, 0, 0);
#pragma unroll
                    for (int r = 0; r < 4; ++r) {
                        float w = sspf(d[r]) * rc;
                        acc[nt][r] = fmaf(w, (float)hv[nt][r], acc[nt][r]);
                    }
                }
            }
        }
        // reduce across the 16-edge (l15) dimension
#pragma unroll
        for (int m = 1; m <= 8; m <<= 1)
#pragma unroll
            for (int nt = 0; nt < 8; ++nt)
#pragma unroll
                for (int r = 0; r < 4; ++r)
                    acc[nt][r] += __shfl_xor(acc[nt][r], m, 64);
        if (l15 == 0) {
#pragma unroll
            for (int nt = 0; nt < 8; ++nt) {
                float4 o = {acc[nt][0], acc[nt][1], acc[nt][2], acc[nt][3]};
                *(float4*)(agg + (size_t)i * 128 + nt * 16 + q * 4) = o;
            }
        }
    }
}

extern "C" void kernel_launch(void* const* d_in, const int* in_sizes, int n_in,
                              void* d_out, int out_size, void* d_ws, size_t ws_size,
                              hipStream_t stream) {
    const float* x     = (const float*)d_in[0];
    const float* f_ij  = (const float*)d_in[1];
    const int*   idx_i = (const int*)d_in[2];
    const int*   idx_j = (const int*)d_in[3];
    const float* rcut  = (const float*)d_in[4];
    const float* W_in  = (const float*)d_in[5];
    const float* b_in  = (const float*)d_in[6];
    const float* W_f   = (const float*)d_in[7];
    const float* b_f   = (const float*)d_in[8];
    const float* W_out = (const float*)d_in[9];
    const float* b_out = (const float*)d_in[10];

    const int N = in_sizes[0] / 128;  // 50000
    const int P = in_sizes[2];        // 1600000

    // workspace layout (16B-aligned chunks)
    char* ws = (char*)d_ws;
    size_t off = 0;
    auto alloc = [&](size_t bytes) {
        void* ptr = ws + off;
        off += (bytes + 15) & ~(size_t)15;
        return ptr;
    };
    int* counts  = (int*)alloc((size_t)N * 4 + 16);  // gtot rides at counts[N..]
    int* gtot    = counts + N;
    int* starts  = (int*)alloc((size_t)N * 4);
    int* cursor  = (int*)alloc((size_t)N * 4);
    _Float16* h16 = (_Float16*)alloc((size_t)N * 128 * 2);
    int2* meta   = (int2*)alloc((size_t)P * 8);
    size_t base_need = off;
    const bool use_ef = (base_need + (size_t)P * 24 * 2 + 64) <= ws_size;
    _Float16* ef = nullptr;
    int* pidx = nullptr;
    if (use_ef) ef = (_Float16*)alloc((size_t)P * 24 * 2 + 64);
    else        pidx = (int*)alloc((size_t)P * 4);

    float* agg = (float*)d_out;  // gather writes agg; gemm_out runs in-place

    const int mblocks = (N + 63) / 64;  // 782
    const int cblocks = 768;
    const int NB = (N + 255) / 256;

    hipMemsetAsync(counts, 0, (size_t)N * 4 + 16, stream);  // counts + gtot
    gemm_in_count_kernel<<<mblocks + cblocks, 256, 0, stream>>>(
        x, W_in, b_in, h16, N, idx_i, counts, P, mblocks);
    alloc_starts_kernel<<<NB, 256, 0, stream>>>(counts, starts, cursor, gtot, N);
    if (use_ef) {
        fill_kernel<true><<<(P + 255) / 256, 256, 0, stream>>>(
            idx_i, idx_j, rcut, f_ij, cursor, ef, meta, pidx, P);
        gather_mfma_kernel<true><<<2048, 256, 0, stream>>>(
            ef, meta, pidx, f_ij, W_f, b_f, h16, starts, counts, agg, N);
    } else {
        fill_kernel<false><<<(P + 255) / 256, 256, 0, stream>>>(
            idx_i, idx_j, rcut, f_ij, cursor, ef, meta, pidx, P);
        gather_mfma_kernel<false><<<2048, 256, 0, stream>>>(
            ef, meta, pidx, f_ij, W_f, b_f, h16, starts, counts, agg, N);
    }
    gemm_out_kernel<<<mblocks, 256, 0, stream>>>(agg, W_out, b_out, (float*)d_out, N);
}